// Round 3
// baseline (278.066 us; speedup 1.0000x reference)
//
#include <hip/hip_runtime.h>
#include <hip/hip_fp8.h>

#define NV 4
#define NB 2048
#define ND 512
#define NN 8192
// sim = cos/TEMP, TEMP=0.5 -> scale 2.0

typedef int int8v __attribute__((ext_vector_type(8)));
typedef int int4v __attribute__((ext_vector_type(4)));
typedef float floatx4 __attribute__((ext_vector_type(4)));
#define SCALE1 0x7F7F7F7Fu  // E8M0 bytes 127 -> 2^0 = 1.0

// ---------------- normalize: x[N,D] f32 -> xn[N,D] fp8 e4m3 (unit rows) ----
__global__ __launch_bounds__(256) void normalize_k(const float* __restrict__ x,
                                                   unsigned char* __restrict__ xn,
                                                   float* __restrict__ sumexp,
                                                   float* __restrict__ out) {
  if (threadIdx.x < 4) sumexp[blockIdx.x * 4 + threadIdx.x] = 0.0f;
  if (blockIdx.x == 0 && threadIdx.x == 0) out[0] = 0.0f;

  const int row = blockIdx.x * 4 + (threadIdx.x >> 6);  // one wave per row
  const int l = threadIdx.x & 63;                        // lane: cols [8l, 8l+8)
  const float4* xr = (const float4*)(x + (size_t)row * ND);
  float4 v0 = xr[l * 2 + 0];
  float4 v1 = xr[l * 2 + 1];
  float ss = v0.x * v0.x + v0.y * v0.y + v0.z * v0.z + v0.w * v0.w +
             v1.x * v1.x + v1.y * v1.y + v1.z * v1.z + v1.w * v1.w;
#pragma unroll
  for (int off = 32; off > 0; off >>= 1) ss += __shfl_xor(ss, off, 64);
  const float inv = 1.0f / fmaxf(sqrtf(ss), 1e-8f);
  union { unsigned char b[8]; uint2 u; } pk;
  pk.b[0] = __hip_fp8_e4m3(v0.x * inv).__x;
  pk.b[1] = __hip_fp8_e4m3(v0.y * inv).__x;
  pk.b[2] = __hip_fp8_e4m3(v0.z * inv).__x;
  pk.b[3] = __hip_fp8_e4m3(v0.w * inv).__x;
  pk.b[4] = __hip_fp8_e4m3(v1.x * inv).__x;
  pk.b[5] = __hip_fp8_e4m3(v1.y * inv).__x;
  pk.b[6] = __hip_fp8_e4m3(v1.z * inv).__x;
  pk.b[7] = __hip_fp8_e4m3(v1.w * inv).__x;
  *(uint2*)(xn + (size_t)row * ND + l * 8) = pk.u;
}

// ---------------- fused sim GEMM + exp/mask epilogue, triangular, fp8-MX ----
// R10 = R9 with FIXED addrspace casts. R9's GLL16 truncated a generic shared
// pointer through (unsigned int) — if the generic representation's low bits
// aren't the LDS offset, every DMA write faults -> container kill. Now uses
// direct C-style addrspacecasts (the canonical m97/m201 pattern).
//
// Schedule (re-audited): per K-tile, 2 phases (A-half mh=0/1). Each phase:
//   {ds_read frags, issue gll stages} -> s_barrier -> lgkmcnt(0) ->
//   setprio(1) 16 MFMA setprio(0) -> s_barrier
// The per-phase lgkmcnt(0) BEFORE the MFMAs means every wave's ds_reads are
// drained before the end-of-phase barrier => gll writes issued in any later
// phase into that region are race-free.
// Staging ledger (region death established >=1 full barrier before issue):
//   p1(t): A1(K_{t+1}) [read p2(t-1)] ; B0(K_{t+1}) [read p1(t-1)]
//   p2(t): B1(K_{t+1}) [read p1(t-1)] ; A0(K_{t+2}) [read p1(t), same iter]
// vmcnt: prologue 10 issues -> vmcnt(2); steady-state boundary vmcnt(2)
// (K_{t+1} landed, A0(K_{t+2}) in flight); vmcnt(0) only at t==2 tail.
// LDS swizzle (verified R7/R8): LDS row r chunk c holds global chunk c^(r&7);
// gll writes linearly (lane l -> row l>>3, chunk l&7) with source chunk
// pre-XORed by (l&7)^(l>>3); read side fo=(2q+j)^s with s==row&7.
__global__ __launch_bounds__(512, 2) void sim_k(const unsigned char* __restrict__ xn,
                                                float* __restrict__ sumexp,
                                                float* __restrict__ pos) {
#define TS (256 * 128)
  __shared__ unsigned char As[2 * TS];  // 64 KiB (double-buffered A tile)
  __shared__ unsigned char Bs[2 * TS];  // 64 KiB
  const int tid = threadIdx.x;
  const int l = tid & 63;
  const int m = l & 15, q = l >> 4, s = l & 7;
  const int w = tid >> 6;
  const int wr = w >> 2, wc = w & 3;  // wave tile: rows wr*128, cols wc*64
  const int w8 = w * 8;               // wave's 8-row staging group
  const int l8 = l >> 3;              // lane's row within group (0..7)
  const int csw = ((l & 7) ^ l8) * 16;  // inverse-swizzled source chunk

  // XCD-aware swizzle: 528 = 8*66, bijective; neighbors (same rt) co-XCD.
  const int bid = (blockIdx.x & 7) * 66 + (blockIdx.x >> 3);
  // triangular decode over 32 tiles: bid -> (rt, ct), rt <= ct
  int rt = (int)((65.0f - sqrtf(4225.0f - 8.0f * (float)bid)) * 0.5f);
  rt = rt < 0 ? 0 : (rt > 31 ? 31 : rt);
  while (rt > 0 && (rt * (65 - rt) / 2) > bid) --rt;
  while (rt < 31 && ((rt + 1) * (64 - rt) / 2) <= bid) ++rt;
  const int ct = rt + (bid - rt * (65 - rt) / 2);
  const bool diag = (rt == ct);

  floatx4 acc[8][4] = {};

  const unsigned char* gA = xn + (size_t)rt * 256 * ND;
  const unsigned char* gB = xn + (size_t)ct * 256 * ND;

  // fragment read offsets (swizzled): row ..+m, k-chunks 2q, 2q+1
  const int fo0 = ((2 * q + 0) ^ s) * 16;
  const int fo1 = ((2 * q + 1) ^ s) * 16;

#define SBAR() __builtin_amdgcn_s_barrier()
#define LGKM0() asm volatile("s_waitcnt lgkmcnt(0)" ::: "memory")
#define VMW2() asm volatile("s_waitcnt vmcnt(2)" ::: "memory")
#define VMW0() asm volatile("s_waitcnt vmcnt(0)" ::: "memory")

  // global_load_lds, 16B/lane: LDS dest = wave-uniform base + lane*16 (HW).
  // Direct addrspacecasts (generic->as1 / generic->as3): NO integer traffic.
#define GLL16(gp, lp)                                                        \
  __builtin_amdgcn_global_load_lds(                                          \
      (const __attribute__((address_space(1))) void*)(gp),                   \
      (__attribute__((address_space(3))) void*)(lp), 16, 0, 0)

  // A-half mh covers rows {mh*64..+64} u {128+mh*64..+64}; 2 gll per wave.
#define STAGE_A(slot_, mh_, kt_)                                             \
  do {                                                                       \
    GLL16(gA + (size_t)((mh_) * 64 + w8 + l8) * ND + (kt_) * 128 + csw,      \
          As + (slot_) * TS + ((mh_) * 64 + w8) * 128);                      \
    GLL16(gA + (size_t)(128 + (mh_) * 64 + w8 + l8) * ND + (kt_) * 128 + csw,\
          As + (slot_) * TS + (128 + (mh_) * 64 + w8) * 128);                \
  } while (0)
  // B-half h covers rows h*128..h*128+127; 2 gll per wave.
#define STAGE_B(slot_, h_, kt_)                                              \
  do {                                                                       \
    GLL16(gB + (size_t)((h_) * 128 + w8 + l8) * ND + (kt_) * 128 + csw,      \
          Bs + (slot_) * TS + ((h_) * 128 + w8) * 128);                      \
    GLL16(gB + (size_t)((h_) * 128 + 64 + w8 + l8) * ND + (kt_) * 128 + csw, \
          Bs + (slot_) * TS + ((h_) * 128 + 64 + w8) * 128);                 \
  } while (0)

#define LDFRAG(dst, base, row)                                               \
  do {                                                                       \
    const unsigned char* p_ = (base) + (size_t)(row) * 128;                  \
    dst = __builtin_shufflevector(*(const int4v*)(p_ + fo0),                 \
                                  *(const int4v*)(p_ + fo1),                 \
                                  0, 1, 2, 3, 4, 5, 6, 7);                   \
  } while (0)

#define MFMA4(mt, afv)                                                       \
  acc[mt][0] = __builtin_amdgcn_mfma_scale_f32_16x16x128_f8f6f4(             \
      afv, bf0, acc[mt][0], 0, 0, 0, SCALE1, 0, SCALE1);                     \
  acc[mt][1] = __builtin_amdgcn_mfma_scale_f32_16x16x128_f8f6f4(             \
      afv, bf1, acc[mt][1], 0, 0, 0, SCALE1, 0, SCALE1);                     \
  acc[mt][2] = __builtin_amdgcn_mfma_scale_f32_16x16x128_f8f6f4(             \
      afv, bf2, acc[mt][2], 0, 0, 0, SCALE1, 0, SCALE1);                     \
  acc[mt][3] = __builtin_amdgcn_mfma_scale_f32_16x16x128_f8f6f4(             \
      afv, bf3, acc[mt][3], 0, 0, 0, SCALE1, 0, SCALE1)

  // prologue: K0 complete (8 gll) + A0(K1) (2 gll); wait oldest 8 -> vmcnt(2)
  STAGE_A(0, 0, 0);
  STAGE_A(0, 1, 0);
  STAGE_B(0, 0, 0);
  STAGE_B(0, 1, 0);
  STAGE_A(1, 0, 1);
  VMW2();
  SBAR();

#pragma unroll
  for (int t = 0; t < 4; ++t) {
    const unsigned char* Asl = As + (t & 1) * TS;
    const unsigned char* Bsl = Bs + (t & 1) * TS;
    const int os = (t & 1) ^ 1;
    int8v af0, af1, af2, af3, bf0, bf1, bf2, bf3;
    // ---------------- phase 1 (mh = 0): reads A0 + all B ----------------
    LDFRAG(af0, Asl, wr * 128 + 0 * 16 + m);
    LDFRAG(af1, Asl, wr * 128 + 1 * 16 + m);
    LDFRAG(af2, Asl, wr * 128 + 2 * 16 + m);
    LDFRAG(af3, Asl, wr * 128 + 3 * 16 + m);
    LDFRAG(bf0, Bsl, wc * 64 + 0 * 16 + m);
    LDFRAG(bf1, Bsl, wc * 64 + 1 * 16 + m);
    LDFRAG(bf2, Bsl, wc * 64 + 2 * 16 + m);
    LDFRAG(bf3, Bsl, wc * 64 + 3 * 16 + m);
    if (t < 3) { STAGE_A(os, 1, t + 1); STAGE_B(os, 0, t + 1); }
    SBAR();
    LGKM0();
    __builtin_amdgcn_s_setprio(1);
    MFMA4(0, af0);
    MFMA4(1, af1);
    MFMA4(2, af2);
    MFMA4(3, af3);
    __builtin_amdgcn_s_setprio(0);
    SBAR();  // all waves' phase-1 ds_reads drained (lgkm0 above) => regions dead
    // ---------------- phase 2 (mh = 1): reads A1; B kept in regs --------
    LDFRAG(af0, Asl, wr * 128 + 64 + 0 * 16 + m);
    LDFRAG(af1, Asl, wr * 128 + 64 + 1 * 16 + m);
    LDFRAG(af2, Asl, wr * 128 + 64 + 2 * 16 + m);
    LDFRAG(af3, Asl, wr * 128 + 64 + 3 * 16 + m);
    if (t < 3) STAGE_B(os, 1, t + 1);
    if (t < 2) STAGE_A(t & 1, 0, t + 2);  // into A0(K_t)'s region (dead)
    SBAR();
    LGKM0();
    __builtin_amdgcn_s_setprio(1);
    MFMA4(4, af0);
    MFMA4(5, af1);
    MFMA4(6, af2);
    MFMA4(7, af3);
    __builtin_amdgcn_s_setprio(0);
    if (t < 2) VMW2();       // K_{t+1} landed; only A0(K_{t+2}) outstanding
    else if (t == 2) VMW0(); // tail drain: K3 fully landed
    SBAR();
  }

  // epilogue: s = 2*acc; masked cols ((c-r)%B==0) store pos, skip sums.
  // Row sums always; col sums + pos mirror only on off-diagonal tiles.
  const int r0 = rt * 256 + wr * 128;
  const int c0 = ct * 256 + wc * 64;
  float cs[4] = {0.f, 0.f, 0.f, 0.f};  // per-nt column partials (this lane's q)
#pragma unroll
  for (int mt = 0; mt < 8; ++mt) {
    float rs[4] = {0.f, 0.f, 0.f, 0.f};
#pragma unroll
    for (int nt = 0; nt < 4; ++nt) {
      const int c = c0 + nt * 16 + m;  // C layout: col = lane&15
#pragma unroll
      for (int reg = 0; reg < 4; ++reg) {
        const int r = r0 + mt * 16 + q * 4 + reg;  // row = quad*4 + reg
        const float sv = acc[mt][nt][reg] * 2.0f;
        if (((c - r) & (NB - 1)) == 0) {
          pos[r * NV + (c >> 11)] = sv;  // includes j==i (unused later)
          if (!diag) pos[c * NV + (r >> 11)] = sv;
        } else {
          const float e = __expf(sv);
          rs[reg] += e;
          cs[nt] += e;
        }
      }
    }
    // reduce rows across the 16-lane column dimension (m)
#pragma unroll
    for (int off = 1; off < 16; off <<= 1) {
#pragma unroll
      for (int reg = 0; reg < 4; ++reg) rs[reg] += __shfl_xor(rs[reg], off, 64);
    }
    if (m < 4) atomicAdd(&sumexp[r0 + mt * 16 + q * 4 + m], rs[m]);
  }
  if (!diag) {
    // reduce cols across the 4-quad row dimension (q)
#pragma unroll
    for (int nt = 0; nt < 4; ++nt) {
      cs[nt] += __shfl_xor(cs[nt], 16, 64);
      cs[nt] += __shfl_xor(cs[nt], 32, 64);
    }
    if (q == 0) {
#pragma unroll
      for (int nt = 0; nt < 4; ++nt)
        atomicAdd(&sumexp[c0 + nt * 16 + m], cs[nt]);
    }
  }
}

// ---------------- finalize: scalar loss -------------------------------------
__global__ __launch_bounds__(256) void finalize_k(
    const float* __restrict__ sumexp, const float* __restrict__ pos,
    float* __restrict__ out) {
  const int r = blockIdx.x * 256 + threadIdx.x;
  const float se = sumexp[r];
  const int i = r >> 11;  // view index
  float local = 0.0f;
#pragma unroll
  for (int j = 0; j < NV; ++j) {
    if (j == i) continue;
    const float p = pos[r * NV + j];
    local += logf(__expf(p) + se) - p;  // logaddexp(pos, lse_neg) - pos
  }
  local *= (1.0f / NB);
#pragma unroll
  for (int off = 32; off > 0; off >>= 1) local += __shfl_xor(local, off, 64);
  if ((threadIdx.x & 63) == 0) atomicAdd(out, local);
}

extern "C" void kernel_launch(void* const* d_in, const int* in_sizes, int n_in,
                              void* d_out, int out_size, void* d_ws,
                              size_t ws_size, hipStream_t stream) {
  const float* x = (const float*)d_in[0];
  float* out = (float*)d_out;
  char* ws = (char*)d_ws;
  unsigned char* xn = (unsigned char*)ws;                 // 4 MB fp8
  float* sumexp = (float*)(ws + (size_t)NN * ND);         // 32 KB
  float* pos = (float*)(ws + (size_t)NN * ND + NN * 4);   // 128 KB

  normalize_k<<<NN / 4, 256, 0, stream>>>(x, xn, sumexp, out);
  sim_k<<<32 * 33 / 2, 512, 0, stream>>>(xn, sumexp, pos);
  finalize_k<<<NN / 256, 256, 0, stream>>>(sumexp, pos, out);
}

// Round 4
// 123.070 us; speedup vs baseline: 2.2594x; 2.2594x over previous
//
#include <hip/hip_runtime.h>
#include <hip/hip_fp8.h>

#define NV 4
#define NB 2048
#define ND 512
#define NN 8192
// sim = cos/TEMP, TEMP=0.5 -> scale 2.0

typedef int int8v __attribute__((ext_vector_type(8)));
typedef int int4v __attribute__((ext_vector_type(4)));
typedef float floatx4 __attribute__((ext_vector_type(4)));
#define SCALE1 0x7F7F7F7Fu  // E8M0 bytes 127 -> 2^0 = 1.0

// ---------------- normalize: x[N,D] f32 -> xn[N,D] fp8 e4m3 (unit rows) ----
__global__ __launch_bounds__(256) void normalize_k(const float* __restrict__ x,
                                                   unsigned char* __restrict__ xn,
                                                   float* __restrict__ sumexp,
                                                   float* __restrict__ out) {
  if (threadIdx.x < 4) sumexp[blockIdx.x * 4 + threadIdx.x] = 0.0f;
  if (blockIdx.x == 0 && threadIdx.x == 0) out[0] = 0.0f;

  const int row = blockIdx.x * 4 + (threadIdx.x >> 6);  // one wave per row
  const int l = threadIdx.x & 63;                        // lane: cols [8l, 8l+8)
  const float4* xr = (const float4*)(x + (size_t)row * ND);
  float4 v0 = xr[l * 2 + 0];
  float4 v1 = xr[l * 2 + 1];
  float ss = v0.x * v0.x + v0.y * v0.y + v0.z * v0.z + v0.w * v0.w +
             v1.x * v1.x + v1.y * v1.y + v1.z * v1.z + v1.w * v1.w;
#pragma unroll
  for (int off = 32; off > 0; off >>= 1) ss += __shfl_xor(ss, off, 64);
  const float inv = 1.0f / fmaxf(sqrtf(ss), 1e-8f);
  union { unsigned char b[8]; uint2 u; } pk;
  pk.b[0] = __hip_fp8_e4m3(v0.x * inv).__x;
  pk.b[1] = __hip_fp8_e4m3(v0.y * inv).__x;
  pk.b[2] = __hip_fp8_e4m3(v0.z * inv).__x;
  pk.b[3] = __hip_fp8_e4m3(v0.w * inv).__x;
  pk.b[4] = __hip_fp8_e4m3(v1.x * inv).__x;
  pk.b[5] = __hip_fp8_e4m3(v1.y * inv).__x;
  pk.b[6] = __hip_fp8_e4m3(v1.z * inv).__x;
  pk.b[7] = __hip_fp8_e4m3(v1.w * inv).__x;
  *(uint2*)(xn + (size_t)row * ND + l * 8) = pk.u;
}

// ---------------- fused sim GEMM + exp/mask epilogue, triangular, fp8-MX ----
// R11 = R10 with the t-loop ROLLED (#pragma unroll 1).
// R10 post-mortem: full unroll hoisted 4 iterations' staging addresses ->
// arch-VGPR exhaustion -> acc/addr spilled to scratch. Counter signature:
// WRITE_SIZE 3.4->198 MB, FETCH 17->324 MB (535 MB HBM traffic on a kernel
// that writes 160 KB), MfmaUtil 3%. Same failure as R5/R6 (291 MB scratch).
// The phase schedule itself PASSED (absmax 0) — ledger is race-free; it was
// just never measured un-spilled. Only change here: roll the loop.
//
// Schedule (unchanged from R10): per K-tile, 2 phases (A-half mh=0/1):
//   {ds_read frags, issue gll stages} -> s_barrier -> lgkmcnt(0) ->
//   setprio(1) 16 MFMA setprio(0) -> s_barrier
// Staging ledger (region death established >=1 full barrier before issue):
//   p1(t): A1(K_{t+1}) [read p2(t-1)] ; B0(K_{t+1}) [read p1(t-1)]
//   p2(t): B1(K_{t+1}) [read p1(t-1)] ; A0(K_{t+2}) [read p1(t), same iter]
// vmcnt (per-wave dynamic counter — valid under rolled loop + uniform
// branches): prologue 10 issues -> vmcnt(2); boundary vmcnt(2) each iter
// (K_{t+1} landed, A0(K_{t+2}) in flight); vmcnt(0) only at t==2 tail.
// LDS swizzle (verified R7/R8): LDS row r chunk c holds global chunk c^(r&7);
// gll writes linearly (lane l -> row l>>3, chunk l&7) with source chunk
// pre-XORed by (l&7)^(l>>3); read side fo=(2q+j)^s with s==row&7.
__global__ __launch_bounds__(512, 2) void sim_k(const unsigned char* __restrict__ xn,
                                                float* __restrict__ sumexp,
                                                float* __restrict__ pos) {
#define TS (256 * 128)
  __shared__ unsigned char As[2 * TS];  // 64 KiB (double-buffered A tile)
  __shared__ unsigned char Bs[2 * TS];  // 64 KiB
  const int tid = threadIdx.x;
  const int l = tid & 63;
  const int m = l & 15, q = l >> 4, s = l & 7;
  const int w = tid >> 6;
  const int wr = w >> 2, wc = w & 3;  // wave tile: rows wr*128, cols wc*64
  const int w8 = w * 8;               // wave's 8-row staging group
  const int l8 = l >> 3;              // lane's row within group (0..7)
  const int csw = ((l & 7) ^ l8) * 16;  // inverse-swizzled source chunk

  // XCD-aware swizzle: 528 = 8*66, bijective; neighbors (same rt) co-XCD.
  const int bid = (blockIdx.x & 7) * 66 + (blockIdx.x >> 3);
  // triangular decode over 32 tiles: bid -> (rt, ct), rt <= ct
  int rt = (int)((65.0f - sqrtf(4225.0f - 8.0f * (float)bid)) * 0.5f);
  rt = rt < 0 ? 0 : (rt > 31 ? 31 : rt);
  while (rt > 0 && (rt * (65 - rt) / 2) > bid) --rt;
  while (rt < 31 && ((rt + 1) * (64 - rt) / 2) <= bid) ++rt;
  const int ct = rt + (bid - rt * (65 - rt) / 2);
  const bool diag = (rt == ct);

  floatx4 acc[8][4] = {};

  const unsigned char* gA = xn + (size_t)rt * 256 * ND;
  const unsigned char* gB = xn + (size_t)ct * 256 * ND;

  // fragment read offsets (swizzled): row ..+m, k-chunks 2q, 2q+1
  const int fo0 = ((2 * q + 0) ^ s) * 16;
  const int fo1 = ((2 * q + 1) ^ s) * 16;

#define SBAR() __builtin_amdgcn_s_barrier()
#define LGKM0() asm volatile("s_waitcnt lgkmcnt(0)" ::: "memory")
#define VMW2() asm volatile("s_waitcnt vmcnt(2)" ::: "memory")
#define VMW0() asm volatile("s_waitcnt vmcnt(0)" ::: "memory")

  // global_load_lds, 16B/lane: LDS dest = wave-uniform base + lane*16 (HW).
#define GLL16(gp, lp)                                                        \
  __builtin_amdgcn_global_load_lds(                                          \
      (const __attribute__((address_space(1))) void*)(gp),                   \
      (__attribute__((address_space(3))) void*)(lp), 16, 0, 0)

  // A-half mh covers rows {mh*64..+64} u {128+mh*64..+64}; 2 gll per wave.
#define STAGE_A(slot_, mh_, kt_)                                             \
  do {                                                                       \
    GLL16(gA + (size_t)((mh_) * 64 + w8 + l8) * ND + (kt_) * 128 + csw,      \
          As + (slot_) * TS + ((mh_) * 64 + w8) * 128);                      \
    GLL16(gA + (size_t)(128 + (mh_) * 64 + w8 + l8) * ND + (kt_) * 128 + csw,\
          As + (slot_) * TS + (128 + (mh_) * 64 + w8) * 128);                \
  } while (0)
  // B-half h covers rows h*128..h*128+127; 2 gll per wave.
#define STAGE_B(slot_, h_, kt_)                                              \
  do {                                                                       \
    GLL16(gB + (size_t)((h_) * 128 + w8 + l8) * ND + (kt_) * 128 + csw,      \
          Bs + (slot_) * TS + ((h_) * 128 + w8) * 128);                      \
    GLL16(gB + (size_t)((h_) * 128 + 64 + w8 + l8) * ND + (kt_) * 128 + csw, \
          Bs + (slot_) * TS + ((h_) * 128 + 64 + w8) * 128);                 \
  } while (0)

#define LDFRAG(dst, base, row)                                               \
  do {                                                                       \
    const unsigned char* p_ = (base) + (size_t)(row) * 128;                  \
    dst = __builtin_shufflevector(*(const int4v*)(p_ + fo0),                 \
                                  *(const int4v*)(p_ + fo1),                 \
                                  0, 1, 2, 3, 4, 5, 6, 7);                   \
  } while (0)

#define MFMA4(mt, afv)                                                       \
  acc[mt][0] = __builtin_amdgcn_mfma_scale_f32_16x16x128_f8f6f4(             \
      afv, bf0, acc[mt][0], 0, 0, 0, SCALE1, 0, SCALE1);                     \
  acc[mt][1] = __builtin_amdgcn_mfma_scale_f32_16x16x128_f8f6f4(             \
      afv, bf1, acc[mt][1], 0, 0, 0, SCALE1, 0, SCALE1);                     \
  acc[mt][2] = __builtin_amdgcn_mfma_scale_f32_16x16x128_f8f6f4(             \
      afv, bf2, acc[mt][2], 0, 0, 0, SCALE1, 0, SCALE1);                     \
  acc[mt][3] = __builtin_amdgcn_mfma_scale_f32_16x16x128_f8f6f4(             \
      afv, bf3, acc[mt][3], 0, 0, 0, SCALE1, 0, SCALE1)

  // prologue: K0 complete (8 gll) + A0(K1) (2 gll); wait oldest 8 -> vmcnt(2)
  STAGE_A(0, 0, 0);
  STAGE_A(0, 1, 0);
  STAGE_B(0, 0, 0);
  STAGE_B(0, 1, 0);
  STAGE_A(1, 0, 1);
  VMW2();
  SBAR();

#pragma unroll 1  // ROLLED — R10's full unroll hoisted addrs -> 500 MB scratch
  for (int t = 0; t < 4; ++t) {
    const unsigned char* Asl = As + (t & 1) * TS;
    const unsigned char* Bsl = Bs + (t & 1) * TS;
    const int os = (t & 1) ^ 1;
    int8v af0, af1, af2, af3, bf0, bf1, bf2, bf3;
    // ---------------- phase 1 (mh = 0): reads A0 + all B ----------------
    LDFRAG(af0, Asl, wr * 128 + 0 * 16 + m);
    LDFRAG(af1, Asl, wr * 128 + 1 * 16 + m);
    LDFRAG(af2, Asl, wr * 128 + 2 * 16 + m);
    LDFRAG(af3, Asl, wr * 128 + 3 * 16 + m);
    LDFRAG(bf0, Bsl, wc * 64 + 0 * 16 + m);
    LDFRAG(bf1, Bsl, wc * 64 + 1 * 16 + m);
    LDFRAG(bf2, Bsl, wc * 64 + 2 * 16 + m);
    LDFRAG(bf3, Bsl, wc * 64 + 3 * 16 + m);
    if (t < 3) { STAGE_A(os, 1, t + 1); STAGE_B(os, 0, t + 1); }
    SBAR();
    LGKM0();
    __builtin_amdgcn_s_setprio(1);
    MFMA4(0, af0);
    MFMA4(1, af1);
    MFMA4(2, af2);
    MFMA4(3, af3);
    __builtin_amdgcn_s_setprio(0);
    SBAR();  // all waves' phase-1 ds_reads drained (lgkm0 above) => regions dead
    // ---------------- phase 2 (mh = 1): reads A1; B kept in regs --------
    LDFRAG(af0, Asl, wr * 128 + 64 + 0 * 16 + m);
    LDFRAG(af1, Asl, wr * 128 + 64 + 1 * 16 + m);
    LDFRAG(af2, Asl, wr * 128 + 64 + 2 * 16 + m);
    LDFRAG(af3, Asl, wr * 128 + 64 + 3 * 16 + m);
    if (t < 3) STAGE_B(os, 1, t + 1);
    if (t < 2) STAGE_A(t & 1, 0, t + 2);  // into A0(K_t)'s region (dead)
    SBAR();
    LGKM0();
    __builtin_amdgcn_s_setprio(1);
    MFMA4(4, af0);
    MFMA4(5, af1);
    MFMA4(6, af2);
    MFMA4(7, af3);
    __builtin_amdgcn_s_setprio(0);
    if (t < 2) VMW2();       // K_{t+1} landed; only A0(K_{t+2}) outstanding
    else if (t == 2) VMW0(); // tail drain: K3 fully landed
    SBAR();
  }

  // epilogue: s = 2*acc; masked cols ((c-r)%B==0) store pos, skip sums.
  // Row sums always; col sums + pos mirror only on off-diagonal tiles.
  const int r0 = rt * 256 + wr * 128;
  const int c0 = ct * 256 + wc * 64;
  float cs[4] = {0.f, 0.f, 0.f, 0.f};  // per-nt column partials (this lane's q)
#pragma unroll
  for (int mt = 0; mt < 8; ++mt) {
    float rs[4] = {0.f, 0.f, 0.f, 0.f};
#pragma unroll
    for (int nt = 0; nt < 4; ++nt) {
      const int c = c0 + nt * 16 + m;  // C layout: col = lane&15
#pragma unroll
      for (int reg = 0; reg < 4; ++reg) {
        const int r = r0 + mt * 16 + q * 4 + reg;  // row = quad*4 + reg
        const float sv = acc[mt][nt][reg] * 2.0f;
        if (((c - r) & (NB - 1)) == 0) {
          pos[r * NV + (c >> 11)] = sv;  // includes j==i (unused later)
          if (!diag) pos[c * NV + (r >> 11)] = sv;
        } else {
          const float e = __expf(sv);
          rs[reg] += e;
          cs[nt] += e;
        }
      }
    }
    // reduce rows across the 16-lane column dimension (m)
#pragma unroll
    for (int off = 1; off < 16; off <<= 1) {
#pragma unroll
      for (int reg = 0; reg < 4; ++reg) rs[reg] += __shfl_xor(rs[reg], off, 64);
    }
    if (m < 4) atomicAdd(&sumexp[r0 + mt * 16 + q * 4 + m], rs[m]);
  }
  if (!diag) {
    // reduce cols across the 4-quad row dimension (q)
#pragma unroll
    for (int nt = 0; nt < 4; ++nt) {
      cs[nt] += __shfl_xor(cs[nt], 16, 64);
      cs[nt] += __shfl_xor(cs[nt], 32, 64);
    }
    if (q == 0) {
#pragma unroll
      for (int nt = 0; nt < 4; ++nt)
        atomicAdd(&sumexp[c0 + nt * 16 + m], cs[nt]);
    }
  }
}

// ---------------- finalize: scalar loss -------------------------------------
__global__ __launch_bounds__(256) void finalize_k(
    const float* __restrict__ sumexp, const float* __restrict__ pos,
    float* __restrict__ out) {
  const int r = blockIdx.x * 256 + threadIdx.x;
  const float se = sumexp[r];
  const int i = r >> 11;  // view index
  float local = 0.0f;
#pragma unroll
  for (int j = 0; j < NV; ++j) {
    if (j == i) continue;
    const float p = pos[r * NV + j];
    local += logf(__expf(p) + se) - p;  // logaddexp(pos, lse_neg) - pos
  }
  local *= (1.0f / NB);
#pragma unroll
  for (int off = 32; off > 0; off >>= 1) local += __shfl_xor(local, off, 64);
  if ((threadIdx.x & 63) == 0) atomicAdd(out, local);
}

extern "C" void kernel_launch(void* const* d_in, const int* in_sizes, int n_in,
                              void* d_out, int out_size, void* d_ws,
                              size_t ws_size, hipStream_t stream) {
  const float* x = (const float*)d_in[0];
  float* out = (float*)d_out;
  char* ws = (char*)d_ws;
  unsigned char* xn = (unsigned char*)ws;                 // 4 MB fp8
  float* sumexp = (float*)(ws + (size_t)NN * ND);         // 32 KB
  float* pos = (float*)(ws + (size_t)NN * ND + NN * 4);   // 128 KB

  normalize_k<<<NN / 4, 256, 0, stream>>>(x, xn, sumexp, out);
  sim_k<<<32 * 33 / 2, 512, 0, stream>>>(xn, sumexp, pos);
  finalize_k<<<NN / 256, 256, 0, stream>>>(sumexp, pos, out);
}